// Round 3
// baseline (1095.877 us; speedup 1.0000x reference)
//
#include <hip/hip_runtime.h>
#include <cstdint>

typedef __attribute__((ext_vector_type(8))) short bf16x8;
typedef __attribute__((ext_vector_type(4))) float f32x4;

constexpr int NH = 8, NB = 8, SEQ = 1024, DM = 1024, DK = 128;
constexpr int MTOT = NB * SEQ; // 8192

__device__ __forceinline__ unsigned short f2bf(float f) {
    unsigned int u = __float_as_uint(f);
    unsigned int r = (u + 0x7fffu + ((u >> 16) & 1u)) >> 16;
    return (unsigned short)r;
}
__device__ __forceinline__ float bf2f(unsigned int s) {
    return __uint_as_float((s & 0xffffu) << 16);
}
__device__ __forceinline__ void gld16(const void* g, void* l) {
    __builtin_amdgcn_global_load_lds((const __attribute__((address_space(1))) void*)g,
                                     (__attribute__((address_space(3))) void*)l, 16, 0, 0);
}

// ---- convert q/k/v fp32 -> bf16 ----
__global__ __launch_bounds__(256) void convert_kernel(
    const float* __restrict__ q, const float* __restrict__ k, const float* __restrict__ v,
    unsigned short* __restrict__ qb, unsigned short* __restrict__ kb, unsigned short* __restrict__ vb)
{
    const int a = blockIdx.y;
    const float* src = (a == 0) ? q : (a == 1) ? k : v;
    unsigned short* dst = (a == 0) ? qb : (a == 1) ? kb : vb;
    size_t i = ((size_t)blockIdx.x * 256 + threadIdx.x) * 8;
    float4 f0 = *reinterpret_cast<const float4*>(src + i);
    float4 f1 = *reinterpret_cast<const float4*>(src + i + 4);
    uint4 o;
    o.x = (unsigned int)f2bf(f0.x) | ((unsigned int)f2bf(f0.y) << 16);
    o.y = (unsigned int)f2bf(f0.z) | ((unsigned int)f2bf(f0.w) << 16);
    o.z = (unsigned int)f2bf(f1.x) | ((unsigned int)f2bf(f1.y) << 16);
    o.w = (unsigned int)f2bf(f1.z) | ((unsigned int)f2bf(f1.w) << 16);
    *reinterpret_cast<uint4*>(dst + i) = o;
}

// ---- transpose+convert weights: W [R][C] fp32 -> W^T [C][R] bf16 ----
__global__ __launch_bounds__(256) void transpose_w_kernel(
    const float* __restrict__ Wq, const float* __restrict__ Wk,
    const float* __restrict__ Wv, const float* __restrict__ Wo,
    unsigned short* __restrict__ WqT, unsigned short* __restrict__ WkT,
    unsigned short* __restrict__ WvT, unsigned short* __restrict__ WoT)
{
    const int s = blockIdx.y;
    const float* in; unsigned short* out; int R, C;
    if (s < 8)        { in = Wq + (size_t)s * DM * DK;       out = WqT + (size_t)s * DK * DM;       R = DM; C = DK; }
    else if (s < 16)  { in = Wk + (size_t)(s - 8) * DM * DK; out = WkT + (size_t)(s - 8) * DK * DM; R = DM; C = DK; }
    else if (s == 16) { in = Wv; out = WvT; R = DM; C = DK; }
    else              { in = Wo; out = WoT; R = DK; C = DM; }
    const int tc = C / 32;
    const int r0 = (blockIdx.x / tc) * 32, c0 = (blockIdx.x % tc) * 32;
    __shared__ unsigned short t[32][33];
    const int tid = threadIdx.x;
    const int a = tid >> 3, b4 = (tid & 7) * 4;
    float4 f = *reinterpret_cast<const float4*>(&in[(size_t)(r0 + a) * C + c0 + b4]);
    t[a][b4 + 0] = f2bf(f.x); t[a][b4 + 1] = f2bf(f.y);
    t[a][b4 + 2] = f2bf(f.z); t[a][b4 + 3] = f2bf(f.w);
    __syncthreads();
    ushort4 o;
    o.x = t[b4 + 0][a]; o.y = t[b4 + 1][a]; o.z = t[b4 + 2][a]; o.w = t[b4 + 3][a];
    *reinterpret_cast<ushort4*>(&out[(size_t)(c0 + a) * R + r0 + b4]) = o;
}

// ---- K1: projections, all-bf16, gld16 staging + XOR-swizzled LDS ----
__global__ __launch_bounds__(256) void proj_kernel(
    const unsigned short* __restrict__ qb, const unsigned short* __restrict__ kb,
    const unsigned short* __restrict__ vb,
    const unsigned short* __restrict__ WqT, const unsigned short* __restrict__ WkT,
    const unsigned short* __restrict__ WvT,
    unsigned short* __restrict__ qh, unsigned short* __restrict__ kh,
    unsigned short* __restrict__ vt)
{
    const int m0 = blockIdx.x * 128;
    const int g  = blockIdx.y;
    const unsigned short* A; const unsigned short* Bt;
    if (g < 8)       { A = qb; Bt = WqT + (size_t)g * DK * DM; }
    else if (g < 16) { A = kb; Bt = WkT + (size_t)(g - 8) * DK * DM; }
    else             { A = vb; Bt = WvT; }

    __shared__ unsigned short As[128][32];
    __shared__ unsigned short Bs[128][32];

    const int tid = threadIdx.x, wave = tid >> 6, lane = tid & 63, quad = lane >> 4, l15 = lane & 15;
    const int wm = (wave & 1) * 64, wn = (wave >> 1) * 64;

    f32x4 acc[4][4];
    for (int mi = 0; mi < 4; ++mi)
        for (int ni = 0; ni < 4; ++ni)
            acc[mi][ni] = (f32x4){0.f, 0.f, 0.f, 0.f};

    const int sr = tid >> 2, sc = tid & 3;
    const int swz = sc ^ ((sr >> 1) & 3);
    const unsigned short* gA0 = A  + (size_t)(m0 + sr) * DM + swz * 8;
    const unsigned short* gB0 = Bt + (size_t)sr * DM + swz * 8;
    char* lA = (char*)&As[0][0] + wave * 1024;
    char* lB = (char*)&Bs[0][0] + wave * 1024;

    for (int k0 = 0; k0 < DM; k0 += 32) {
        __syncthreads();
        gld16(gA0 + k0, lA); gld16(gA0 + k0 + 64 * DM, lA + 4096);
        gld16(gB0 + k0, lB); gld16(gB0 + k0 + 64 * DM, lB + 4096);
        __syncthreads();
        bf16x8 af[4], bf[4];
        for (int mi = 0; mi < 4; ++mi) {
            int row = wm + mi * 16 + l15;
            af[mi] = *reinterpret_cast<const bf16x8*>(&As[row][(quad ^ ((row >> 1) & 3)) * 8]);
        }
        for (int ni = 0; ni < 4; ++ni) {
            int row = wn + ni * 16 + l15;
            bf[ni] = *reinterpret_cast<const bf16x8*>(&Bs[row][(quad ^ ((row >> 1) & 3)) * 8]);
        }
        for (int mi = 0; mi < 4; ++mi)
            for (int ni = 0; ni < 4; ++ni)
                acc[mi][ni] = __builtin_amdgcn_mfma_f32_16x16x32_bf16(af[mi], bf[ni], acc[mi][ni], 0, 0, 0);
    }

    if (g < 16) {
        unsigned short* C = (g < 8) ? (qh + (size_t)g * MTOT * DK)
                                    : (kh + (size_t)(g - 8) * MTOT * DK);
        for (int mi = 0; mi < 4; ++mi)
            for (int ni = 0; ni < 4; ++ni)
                for (int r = 0; r < 4; ++r)
                    C[(size_t)(m0 + wm + mi * 16 + quad * 4 + r) * DK + wn + ni * 16 + l15] =
                        f2bf(acc[mi][ni][r]);
    } else {
        for (int mi = 0; mi < 4; ++mi)
            for (int ni = 0; ni < 4; ++ni)
                for (int r = 0; r < 4; ++r) {
                    int row = m0 + wm + mi * 16 + quad * 4 + r;  // b*1024 + s
                    int col = wn + ni * 16 + l15;                // dv
                    vt[((size_t)(row >> 10) * DK + col) * SEQ + (row & 1023)] = f2bf(acc[mi][ni][r]);
                }
    }
}

// ---- K2: single-pass causal attention, 32-row Q tiles ----
// Writes unnormalized exp(scores) bf16 into the first 2KB of each attn row slot,
// inv_l per row, and normalized heads.
__global__ __launch_bounds__(256, 4) void attn_kernel(
    const unsigned short* __restrict__ qh, const unsigned short* __restrict__ kh,
    const unsigned short* __restrict__ vt, unsigned short* __restrict__ heads,
    unsigned short* __restrict__ ptil, float* __restrict__ inv_l_g)
{
    const int bx = blockIdx.x;
    const int hb = bx >> 5;
    const int ti = 31 - (bx & 31);      // long tiles dispatched first within each hb group
    const int m0 = ti * 32;
    const int jmax = (m0 + 31) >> 6;
    const int b = hb & 7;

    const unsigned short* qbase = qh + ((size_t)hb * SEQ + m0) * DK;
    const unsigned short* kbase = kh + (size_t)hb * SEQ * DK;
    const unsigned short* vbase = vt + (size_t)b * DK * SEQ;

    __shared__ unsigned short Ks[4][64][32];  // 16 KB, swizzled layout
    __shared__ unsigned short Ps[32][72];     // 4.5 KB
    __shared__ float lred[4][32];
    __shared__ float invl[32];

    const int tid = threadIdx.x, w = tid >> 6, lane = tid & 63, quad = lane >> 4, l15 = lane & 15;
    const float scale = 0.08838834764831843f;  // 1/sqrt(128)

    // Q fragments in registers for the whole kernel
    bf16x8 aq[2][4];
    for (int mt = 0; mt < 2; ++mt)
        for (int ks = 0; ks < 4; ++ks)
            aq[mt][ks] = *reinterpret_cast<const bf16x8*>(
                &qbase[(size_t)(mt * 16 + l15) * DK + ks * 32 + quad * 8]);

    const int sr = tid >> 2, sc = tid & 3;
    const int swz = sc ^ ((sr >> 1) & 3);
    const unsigned short* gK0 = kbase + (size_t)sr * DK + swz * 8;
    char* lK = (char*)&Ks[0][0][0] + w * 1024;

    f32x4 oacc[2][2];
    for (int mt = 0; mt < 2; ++mt)
        for (int n2 = 0; n2 < 2; ++n2)
            oacc[mt][n2] = (f32x4){0.f, 0.f, 0.f, 0.f};
    float l_part[2][4] = {{0.f, 0.f, 0.f, 0.f}, {0.f, 0.f, 0.f, 0.f}};

    for (int j = 0; j <= jmax; ++j) {
        __syncthreads();
        const unsigned short* gKj = gK0 + (size_t)j * 64 * DK;
        for (int ks = 0; ks < 4; ++ks) gld16(gKj + ks * 32, lK + ks * 4096);
        __syncthreads();

        // QK^T: 32x64 tile, wave w owns 16-col slice
        f32x4 sacc[2];
        sacc[0] = (f32x4){0.f, 0.f, 0.f, 0.f};
        sacc[1] = (f32x4){0.f, 0.f, 0.f, 0.f};
        const int n = w * 16 + l15;
        const int ph = (quad ^ ((n >> 1) & 3)) * 8;
        for (int ks = 0; ks < 4; ++ks) {
            bf16x8 bb = *reinterpret_cast<const bf16x8*>(&Ks[ks][n][ph]);
            sacc[0] = __builtin_amdgcn_mfma_f32_16x16x32_bf16(aq[0][ks], bb, sacc[0], 0, 0, 0);
            sacc[1] = __builtin_amdgcn_mfma_f32_16x16x32_bf16(aq[1][ks], bb, sacc[1], 0, 0, 0);
        }
        const int colbase = j * 64 + w * 16 + l15;
        for (int mt = 0; mt < 2; ++mt)
            for (int r = 0; r < 4; ++r) {
                int t = m0 + mt * 16 + quad * 4 + r;
                float e = (colbase <= t) ? __expf(sacc[mt][r] * scale) : 0.f;
                l_part[mt][r] += e;
                Ps[mt * 16 + quad * 4 + r][w * 16 + l15] = f2bf(e);
            }
        __syncthreads();
        { // store unnormalized P-tile (bf16) into attn row slots
            int row = tid >> 3, c0 = (tid & 7) * 8;
            uint4 u = *reinterpret_cast<const uint4*>(&Ps[row][c0]);
            *reinterpret_cast<uint4*>(
                &ptil[(size_t)(hb * SEQ + m0 + row) * 2048 + j * 64 + c0]) = u;
        }
        // P~ . V accumulate (V direct from global, L2-resident)
        for (int ks2 = 0; ks2 < 2; ++ks2)
            for (int mt = 0; mt < 2; ++mt) {
                bf16x8 ap = *reinterpret_cast<const bf16x8*>(&Ps[mt * 16 + l15][ks2 * 32 + quad * 8]);
                for (int n2 = 0; n2 < 2; ++n2) {
                    int dv = w * 32 + n2 * 16 + l15;
                    bf16x8 bv = *reinterpret_cast<const bf16x8*>(
                        &vbase[(size_t)dv * SEQ + j * 64 + ks2 * 32 + quad * 8]);
                    oacc[mt][n2] = __builtin_amdgcn_mfma_f32_16x16x32_bf16(ap, bv, oacc[mt][n2], 0, 0, 0);
                }
            }
    }

    // row-sum reduction: shfl over 16 cols, then across waves via LDS
    for (int mt = 0; mt < 2; ++mt)
        for (int r = 0; r < 4; ++r) {
            float s = l_part[mt][r];
            for (int off = 1; off < 16; off <<= 1) s += __shfl_xor(s, off, 64);
            if (l15 == 0) lred[w][mt * 16 + quad * 4 + r] = s;
        }
    __syncthreads();
    if (tid < 32) {
        float l = lred[0][tid] + lred[1][tid] + lred[2][tid] + lred[3][tid];
        float inv = 1.f / l;
        invl[tid] = inv;
        inv_l_g[hb * SEQ + m0 + tid] = inv;
    }
    __syncthreads();
    for (int mt = 0; mt < 2; ++mt)
        for (int n2 = 0; n2 < 2; ++n2)
            for (int r = 0; r < 4; ++r)
                heads[((size_t)hb * SEQ + m0 + mt * 16 + quad * 4 + r) * DK + w * 32 + n2 * 16 + l15] =
                    f2bf(oacc[mt][n2][r] * invl[mt * 16 + quad * 4 + r]);
}

// ---- normalize: in-place bf16 P~ -> fp32 attn * inv_l, causal zeros ----
__global__ __launch_bounds__(256) void normalize_kernel(
    float* __restrict__ attn, const float* __restrict__ inv_l_g)
{
    const int hb = blockIdx.x >> 6;
    const int t0 = (blockIdx.x & 63) * 16;
    const int tid = threadIdx.x, r = tid >> 4, seg = tid & 15;
    const int t = t0 + r;
    float* rowp = attn + ((size_t)hb * SEQ + t) * SEQ;
    const uint4* src = reinterpret_cast<const uint4*>(rowp);  // bf16 view of first 2KB

    uint4 ld[8];
    for (int i = 0; i < 8; ++i) ld[i] = (uint4){0, 0, 0, 0};
    if (seg * 64 <= t)
        for (int i = 0; i < 8; ++i) ld[i] = src[seg * 8 + i];
    const float inv = inv_l_g[hb * SEQ + t];
    __syncthreads();  // all loads done before any in-place overwrite

    float* dst = rowp + seg * 64;
    for (int i = 0; i < 8; ++i) {
        const int cb = seg * 64 + i * 8;
        f32x4 o0, o1;
        o0[0] = (cb + 0 <= t) ? bf2f(ld[i].x) * inv : 0.f;
        o0[1] = (cb + 1 <= t) ? bf2f(ld[i].x >> 16) * inv : 0.f;
        o0[2] = (cb + 2 <= t) ? bf2f(ld[i].y) * inv : 0.f;
        o0[3] = (cb + 3 <= t) ? bf2f(ld[i].y >> 16) * inv : 0.f;
        o1[0] = (cb + 4 <= t) ? bf2f(ld[i].z) * inv : 0.f;
        o1[1] = (cb + 5 <= t) ? bf2f(ld[i].z >> 16) * inv : 0.f;
        o1[2] = (cb + 6 <= t) ? bf2f(ld[i].w) * inv : 0.f;
        o1[3] = (cb + 7 <= t) ? bf2f(ld[i].w >> 16) * inv : 0.f;
        __builtin_nontemporal_store(o0, (f32x4*)(dst + i * 8));
        __builtin_nontemporal_store(o1, (f32x4*)(dst + i * 8 + 4));
    }
}

// ---- mean over heads ----
__global__ __launch_bounds__(256) void mean_kernel(
    const unsigned short* __restrict__ heads, unsigned short* __restrict__ hmean)
{
    size_t base = ((size_t)blockIdx.x * 256 + threadIdx.x) * 8;
    float s[8] = {0.f, 0.f, 0.f, 0.f, 0.f, 0.f, 0.f, 0.f};
    for (int h = 0; h < 8; ++h) {
        uint4 u = *reinterpret_cast<const uint4*>(&heads[(size_t)h * MTOT * DK + base]);
        s[0] += bf2f(u.x); s[1] += bf2f(u.x >> 16);
        s[2] += bf2f(u.y); s[3] += bf2f(u.y >> 16);
        s[4] += bf2f(u.z); s[5] += bf2f(u.z >> 16);
        s[6] += bf2f(u.w); s[7] += bf2f(u.w >> 16);
    }
    uint4 o;
    o.x = (unsigned int)f2bf(s[0] * 0.125f) | ((unsigned int)f2bf(s[1] * 0.125f) << 16);
    o.y = (unsigned int)f2bf(s[2] * 0.125f) | ((unsigned int)f2bf(s[3] * 0.125f) << 16);
    o.z = (unsigned int)f2bf(s[4] * 0.125f) | ((unsigned int)f2bf(s[5] * 0.125f) << 16);
    o.w = (unsigned int)f2bf(s[6] * 0.125f) | ((unsigned int)f2bf(s[7] * 0.125f) << 16);
    *reinterpret_cast<uint4*>(&hmean[base]) = o;
}

// ---- K3: out = hmean @ Wo ----
__global__ __launch_bounds__(256) void out_kernel(
    const unsigned short* __restrict__ hmean, const unsigned short* __restrict__ WoT,
    float* __restrict__ out)
{
    const int n0 = blockIdx.x * 128, m0 = blockIdx.y * 128;
    __shared__ unsigned short As[128][32];
    __shared__ unsigned short Bs[128][32];

    const int tid = threadIdx.x, wave = tid >> 6, lane = tid & 63, quad = lane >> 4, l15 = lane & 15;
    const int wm = (wave & 1) * 64, wn = (wave >> 1) * 64;

    f32x4 acc[4][4];
    for (int mi = 0; mi < 4; ++mi)
        for (int ni = 0; ni < 4; ++ni)
            acc[mi][ni] = (f32x4){0.f, 0.f, 0.f, 0.f};

    const int sr = tid >> 2, sc = tid & 3;
    const int swz = sc ^ ((sr >> 1) & 3);
    const unsigned short* gA0 = hmean + (size_t)(m0 + sr) * DK + swz * 8;
    const unsigned short* gB0 = WoT + (size_t)(n0 + sr) * DK + swz * 8;
    char* lA = (char*)&As[0][0] + wave * 1024;
    char* lB = (char*)&Bs[0][0] + wave * 1024;

    for (int k0 = 0; k0 < DK; k0 += 32) {
        __syncthreads();
        gld16(gA0 + k0, lA); gld16(gA0 + k0 + 64 * DK, lA + 4096);
        gld16(gB0 + k0, lB); gld16(gB0 + k0 + 64 * DK, lB + 4096);
        __syncthreads();
        bf16x8 af[4], bf[4];
        for (int mi = 0; mi < 4; ++mi) {
            int row = wm + mi * 16 + l15;
            af[mi] = *reinterpret_cast<const bf16x8*>(&As[row][(quad ^ ((row >> 1) & 3)) * 8]);
        }
        for (int ni = 0; ni < 4; ++ni) {
            int row = wn + ni * 16 + l15;
            bf[ni] = *reinterpret_cast<const bf16x8*>(&Bs[row][(quad ^ ((row >> 1) & 3)) * 8]);
        }
        for (int mi = 0; mi < 4; ++mi)
            for (int ni = 0; ni < 4; ++ni)
                acc[mi][ni] = __builtin_amdgcn_mfma_f32_16x16x32_bf16(af[mi], bf[ni], acc[mi][ni], 0, 0, 0);
    }
    for (int mi = 0; mi < 4; ++mi)
        for (int ni = 0; ni < 4; ++ni)
            for (int r = 0; r < 4; ++r)
                out[(size_t)(m0 + wm + mi * 16 + quad * 4 + r) * DM + n0 + wn + ni * 16 + l15] =
                    acc[mi][ni][r];
}

extern "C" void kernel_launch(void* const* d_in, const int* in_sizes, int n_in,
                              void* d_out, int out_size, void* d_ws, size_t ws_size,
                              hipStream_t stream) {
    (void)in_sizes; (void)n_in; (void)out_size; (void)ws_size;
    const float* q  = (const float*)d_in[0];
    const float* k  = (const float*)d_in[1];
    const float* v  = (const float*)d_in[2];
    // d_in[3] = mask: causal tril, applied analytically
    const float* Wq = (const float*)d_in[4];
    const float* Wk = (const float*)d_in[5];
    const float* Wv = (const float*)d_in[6];
    const float* Wo = (const float*)d_in[7];

    float* out  = (float*)d_out;                    // 8,388,608 floats (32 MB)
    float* attn = out + (size_t)NB * SEQ * DM;      // 67,108,864 floats (256 MB)

    // dead d_out space reused as scratch (stream-ordered lifetimes):
    unsigned short* heads = (unsigned short*)d_out;          // [0,16MB) of out region
    unsigned short* qb    = (unsigned short*)d_out + 8388608; // [16,32MB) of out region
    unsigned short* kb    = (unsigned short*)attn;            // attn bytes [0,16MB), dead after proj
    unsigned short* vb    = kb + 8388608;                     // attn bytes [16,32MB)
    unsigned short* ptil  = (unsigned short*)attn;            // bf16 P~ in-place (first 2KB per row)

    unsigned short* ws    = (unsigned short*)d_ws;
    unsigned short* WqT   = ws;                           // 1M shorts
    unsigned short* WkT   = WqT + (size_t)NH * DK * DM;   // 1M
    unsigned short* WvT   = WkT + (size_t)NH * DK * DM;   // 128K
    unsigned short* WoT   = WvT + (size_t)DK * DM;        // 128K
    unsigned short* qh    = WoT + (size_t)DM * DK;        // 8M
    unsigned short* kh    = qh + (size_t)NH * MTOT * DK;  // 8M
    unsigned short* vt    = kh + (size_t)NH * MTOT * DK;  // 1M
    unsigned short* hmean = vt + (size_t)NB * DK * SEQ;   // 1M
    float* inv_l          = (float*)(hmean + (size_t)MTOT * DK);  // 64K floats
    // total ws ~42.7 MB

    convert_kernel<<<dim3(4096, 3), 256, 0, stream>>>(q, k, v, qb, kb, vb);
    transpose_w_kernel<<<dim3(128, 18), 256, 0, stream>>>(Wq, Wk, Wv, Wo, WqT, WkT, WvT, WoT);
    proj_kernel<<<dim3(64, 17), 256, 0, stream>>>(qb, kb, vb, WqT, WkT, WvT, qh, kh, vt);
    attn_kernel<<<2048, 256, 0, stream>>>(qh, kh, vt, heads, ptil, inv_l);
    mean_kernel<<<512, 256, 0, stream>>>(heads, hmean);
    normalize_kernel<<<4096, 256, 0, stream>>>(attn, inv_l);
    out_kernel<<<dim3(8, 64), 256, 0, stream>>>(hmean, WoT, out);
}